// Round 4
// baseline (248.092 us; speedup 1.0000x reference)
//
#include <hip/hip_runtime.h>

#define NP     8732
#define NB     32
#define NOBJ   16
#define NC     81
#define CHUNKS 32
#define CHUNK  273                       // ceil(8732/32)
#define MATCH_BLOCKS (NB * CHUNKS)       // 1024
#define LSE_BLOCKS   2048
#define NROWS  (NB * NP)                 // 279424

__device__ __forceinline__ float sl1f(float x) {
  float d = fabsf(x);
  return d < 1.0f ? 0.5f * d * d : d - 0.5f;
}

__device__ __forceinline__ float iou_box(float tx0, float ty0, float tx1, float ty1,
                                         float ta, float px0, float py0, float px1,
                                         float py1, float pa) {
  float w = fminf(tx1, px1) - fmaxf(tx0, px0);
  float h = fminf(ty1, py1) - fmaxf(ty0, py0);
  w = fmaxf(w, 0.0f); h = fmaxf(h, 0.0f);
  float inter = w * h;
  return inter / (ta + pa - inter);
}

__device__ __forceinline__ float locloss(float tx0, float ty0, float tx1, float ty1,
                                         float4 pr, float4 ld) {
  float gx = ((tx0 + tx1) * 0.5f - pr.x) / (0.1f * pr.z);
  float gy = ((ty0 + ty1) * 0.5f - pr.y) / (0.1f * pr.w);
  float gw = logf((tx1 - tx0) / pr.z) / 0.2f;
  float gh = logf((ty1 - ty0) / pr.w) / 0.2f;
  return sl1f(ld.x - gx) + sl1f(ld.y - gy) + sl1f(ld.z - gw) + sl1f(ld.w - gh);
}

// ---- K1: fused matching (provisional) + per-chunk argmax keys + lse ----
__global__ __launch_bounds__(256) void k1(
    const float* __restrict__ loc, const float* __restrict__ conf,
    const float* __restrict__ targets, const float* __restrict__ priors,
    unsigned long long* __restrict__ bestPrChunk, int* __restrict__ conf_t,
    float* __restrict__ lsum_part, int* __restrict__ pcnt_part,
    float* __restrict__ lse)
{
  const int tid = threadIdx.x;
  if (blockIdx.x < MATCH_BLOCKS) {
    const int b = blockIdx.x >> 5, ch = blockIdx.x & 31;
    const int p0 = ch * CHUNK, p1 = min(NP, p0 + CHUNK);
    __shared__ float tx0[NOBJ], ty0[NOBJ], tx1[NOBJ], ty1[NOBJ], tarea[NOBJ];
    __shared__ int tlab[NOBJ];
    __shared__ unsigned long long sbest[NOBJ];
    __shared__ float redf[4]; __shared__ int redi[4];
    if (tid < NOBJ) {
      const float* tg = targets + (b * NOBJ + tid) * 5;
      float x0 = tg[0], y0 = tg[1], x1 = tg[2], y1 = tg[3];
      tx0[tid] = x0; ty0[tid] = y0; tx1[tid] = x1; ty1[tid] = y1;
      tarea[tid] = (x1 - x0) * (y1 - y0);
      tlab[tid] = (int)tg[4];
      sbest[tid] = 0ull;
    }
    __syncthreads();
    float bv[NOBJ]; int bp[NOBJ];
    #pragma unroll
    for (int n = 0; n < NOBJ; ++n) { bv[n] = -1.0f; bp[n] = 0; }
    float lsum = 0.0f; int pcnt = 0;
    for (int p = p0 + tid; p < p1; p += 256) {
      float4 pr = reinterpret_cast<const float4*>(priors)[p];
      float px0 = pr.x - pr.z * 0.5f, py0 = pr.y - pr.w * 0.5f;
      float px1 = pr.x + pr.z * 0.5f, py1 = pr.y + pr.w * 0.5f;
      float pa = (px1 - px0) * (py1 - py0);
      float bestov = -1.0f; int bestn = 0;
      #pragma unroll
      for (int n = 0; n < NOBJ; ++n) {
        float iou = iou_box(tx0[n], ty0[n], tx1[n], ty1[n], tarea[n],
                            px0, py0, px1, py1, pa);
        if (iou > bv[n]) { bv[n] = iou; bp[n] = p; }      // first occurrence
        if (iou > bestov) { bestov = iou; bestn = n; }    // first occurrence
      }
      int c = (bestov < 0.5f) ? 0 : (tlab[bestn] + 1);
      conf_t[b * NP + p] = c;                             // provisional
      if (c > 0) {
        ++pcnt;
        float4 ld = reinterpret_cast<const float4*>(loc)[b * NP + p];
        lsum += locloss(tx0[bestn], ty0[bestn], tx1[bestn], ty1[bestn], pr, ld);
      }
    }
    // per-truth key: (iou_bits, NP-p) -> equal iou => smaller p wins
    #pragma unroll
    for (int n = 0; n < NOBJ; ++n) {
      unsigned long long key =
          ((unsigned long long)__float_as_uint(bv[n]) << 32) | (unsigned)(NP - bp[n]);
      #pragma unroll
      for (int s = 1; s < 64; s <<= 1) {
        unsigned long long o = __shfl_xor(key, s, 64);
        key = o > key ? o : key;
      }
      if ((tid & 63) == 0) atomicMax(&sbest[n], key);
    }
    #pragma unroll
    for (int s = 32; s >= 1; s >>= 1) {
      lsum += __shfl_xor(lsum, s, 64);
      pcnt += __shfl_xor(pcnt, s, 64);
    }
    if ((tid & 63) == 0) { redf[tid >> 6] = lsum; redi[tid >> 6] = pcnt; }
    __syncthreads();
    if (tid == 0) {
      lsum_part[blockIdx.x] = redf[0] + redf[1] + redf[2] + redf[3];
      pcnt_part[blockIdx.x] = redi[0] + redi[1] + redi[2] + redi[3];
    }
    if (tid < NOBJ) bestPrChunk[(b * NOBJ + tid) * CHUNKS + ch] = sbest[tid];
  } else {
    // lse blocks: 16 lanes per row, grid-stride
    const int lane = tid & 15;
    const int gid = (blockIdx.x - MATCH_BLOCKS) * 16 + (tid >> 4);
    const int stride = LSE_BLOCKS * 16;
    for (int r = gid; r < NROWS; r += stride) {
      const float* row = conf + (size_t)r * NC;
      float x0 = row[lane], x1 = row[lane + 16], x2 = row[lane + 32];
      float x3 = row[lane + 48], x4 = row[lane + 64];
      float x5 = (lane == 0) ? row[80] : -3.0e38f;
      float m = fmaxf(fmaxf(fmaxf(x0, x1), fmaxf(x2, x3)), fmaxf(x4, x5));
      #pragma unroll
      for (int s = 8; s >= 1; s >>= 1) m = fmaxf(m, __shfl_xor(m, s, 16));
      float sum = expf(x0 - m) + expf(x1 - m) + expf(x2 - m) +
                  expf(x3 - m) + expf(x4 - m);
      if (lane == 0) sum += expf(x5 - m);
      #pragma unroll
      for (int s = 8; s >= 1; s >>= 1) sum += __shfl_xor(sum, s, 16);
      if (lane == 0) lse[r] = m + logf(sum);
    }
  }
}

// ---- K2: forced-match fixup (deltas) + finalize accumulators ----
__global__ __launch_bounds__(256) void k2(
    const float* __restrict__ loc, const float* __restrict__ targets,
    const float* __restrict__ priors,
    const unsigned long long* __restrict__ bestPrChunk,
    const float* __restrict__ lsum_part, const int* __restrict__ pcnt_part,
    int* __restrict__ conf_t, int* __restrict__ num_pos,
    float* __restrict__ facc, int* __restrict__ iacc, int* __restrict__ ticket)
{
  const int tid = threadIdx.x;
  __shared__ float stx0[NB][NOBJ], sty0[NB][NOBJ], stx1[NB][NOBJ],
                   sty1[NB][NOBJ], sta[NB][NOBJ];
  __shared__ int slab[NB][NOBJ], fpd[NB][NOBJ];
  __shared__ float redf[4];
  // phase A: truths -> LDS, forced prior per truth, provisional lsum reduce
  for (int e = tid; e < NB * NOBJ; e += 256) {
    const float* tg = targets + e * 5;
    int b = e >> 4, n = e & 15;
    float x0 = tg[0], y0 = tg[1], x1 = tg[2], y1 = tg[3];
    stx0[b][n] = x0; sty0[b][n] = y0; stx1[b][n] = x1; sty1[b][n] = y1;
    sta[b][n] = (x1 - x0) * (y1 - y0);
    slab[b][n] = (int)tg[4];
    const unsigned long long* kp = bestPrChunk + e * CHUNKS;
    unsigned long long key = 0ull;
    #pragma unroll
    for (int c = 0; c < CHUNKS; ++c) {
      unsigned long long o = kp[c];
      key = o > key ? o : key;
    }
    fpd[b][n] = NP - (int)(key & 0xFFFFFFFFull);
  }
  float ls = lsum_part[tid] + lsum_part[tid + 256] +
             lsum_part[tid + 512] + lsum_part[tid + 768];
  #pragma unroll
  for (int s = 32; s >= 1; s >>= 1) ls += __shfl_xor(ls, s, 64);
  if ((tid & 63) == 0) redf[tid >> 6] = ls;
  __syncthreads();
  // phase B: one thread per batch applies overrides as deltas
  float dls = 0.0f; int npos = 0;
  if (tid < NB) {
    const int b = tid;
    int pc = 0;
    #pragma unroll
    for (int c = 0; c < CHUNKS; ++c) pc += pcnt_part[b * CHUNKS + c];
    int fp[NOBJ];
    #pragma unroll
    for (int n = 0; n < NOBJ; ++n) fp[n] = fpd[b][n];
    #pragma unroll
    for (int n = 0; n < NOBJ; ++n) {
      bool valid = true;                      // last truth wins on duplicate prior
      #pragma unroll
      for (int m = n + 1; m < NOBJ; ++m) if (fp[m] == fp[n]) valid = false;
      if (!valid) continue;
      const int p = fp[n];
      float4 pr = reinterpret_cast<const float4*>(priors)[p];
      float px0 = pr.x - pr.z * 0.5f, py0 = pr.y - pr.w * 0.5f;
      float px1 = pr.x + pr.z * 0.5f, py1 = pr.y + pr.w * 0.5f;
      float pa = (px1 - px0) * (py1 - py0);
      float bestov = -1.0f; int bestn = 0;    // recompute provisional (bitwise same)
      #pragma unroll
      for (int q = 0; q < NOBJ; ++q) {
        float iou = iou_box(stx0[b][q], sty0[b][q], stx1[b][q], sty1[b][q],
                            sta[b][q], px0, py0, px1, py1, pa);
        if (iou > bestov) { bestov = iou; bestn = q; }
      }
      int oldc = (bestov < 0.5f) ? 0 : (slab[b][bestn] + 1);
      float4 ld = reinterpret_cast<const float4*>(loc)[b * NP + p];
      float newl = locloss(stx0[b][n], sty0[b][n], stx1[b][n], sty1[b][n], pr, ld);
      float oldl = (oldc > 0)
          ? locloss(stx0[b][bestn], sty0[b][bestn], stx1[b][bestn], sty1[b][bestn], pr, ld)
          : 0.0f;
      dls += newl - oldl;
      npos += (oldc > 0) ? 0 : 1;
      conf_t[b * NP + p] = slab[b][n] + 1;
    }
    npos += pc;
    num_pos[b] = npos;
  }
  #pragma unroll
  for (int s = 32; s >= 1; s >>= 1) {
    dls += __shfl_xor(dls, s, 64);
    npos += __shfl_xor(npos, s, 64);
  }
  if (tid == 0) {
    facc[0] = redf[0] + redf[1] + redf[2] + redf[3] + dls;
    iacc[0] = npos;
    facc[1] = 0.0f; facc[2] = 0.0f; ticket[0] = 0;
  }
}

// ---- K3: ce gather + positive-ce sum + exact top-k + final outputs ----
__global__ __launch_bounds__(1024) void k3(
    const float* __restrict__ conf, const int* __restrict__ conf_t,
    const float* __restrict__ lse, const int* __restrict__ num_pos,
    float* __restrict__ facc, const int* __restrict__ iacc,
    int* __restrict__ ticket, float* __restrict__ out)
{
  const int b = blockIdx.x, tid = threadIdx.x;
  const int wid = tid >> 6, lane = tid & 63;
  __shared__ int   redi2[2][16];
  __shared__ float redfa[16];
  __shared__ int   redia[16];
  float rv[9]; float cepos = 0.0f;
  #pragma unroll
  for (int i = 0; i < 9; ++i) {
    int idx = tid + (i << 10);
    if (idx < NP) {
      int r = b * NP + idx;
      int ct = conf_t[r];
      float ce = lse[r] - conf[(size_t)r * NC + ct];
      if (ct > 0) { cepos += ce; rv[i] = 0.0f; } else rv[i] = ce;
    } else rv[i] = -1.0f;                    // sentinel, never > thr (thr >= 0)
  }
  #pragma unroll
  for (int s = 32; s >= 1; s >>= 1) cepos += __shfl_xor(cepos, s, 64);
  if (lane == 0) redfa[wid] = cepos;
  __syncthreads();
  if (tid == 0) {
    float t = 0.0f;
    #pragma unroll
    for (int w = 0; w < 16; ++w) t += redfa[w];
    atomicAdd(&facc[1], t);
  }
  int k = 3 * num_pos[b];
  if (k > NP - 1) k = NP - 1;
  float tot = 0.0f;
  if (k > 0) {                               // uniform branch (k same block-wide)
    unsigned lo = 0u, hi = 0x7f800000u; int par = 0;
    while (lo < hi) {
      unsigned mid = lo + ((hi - lo) >> 1);
      float thr = __uint_as_float(mid);
      int c = 0;
      #pragma unroll
      for (int i = 0; i < 9; ++i) c += (rv[i] > thr) ? 1 : 0;
      #pragma unroll
      for (int s = 32; s >= 1; s >>= 1) c += __shfl_xor(c, s, 64);
      if (lane == 0) redi2[par][wid] = c;
      __syncthreads();
      int t = 0;
      #pragma unroll
      for (int w = 0; w < 16; ++w) t += redi2[par][w];
      par ^= 1;
      if (t < k) hi = mid; else lo = mid + 1;
    }
    float vk = __uint_as_float(lo);
    int cgt = 0; float s = 0.0f;
    #pragma unroll
    for (int i = 0; i < 9; ++i) {
      float v = rv[i];
      if (v > vk) { ++cgt; s += v; }
    }
    #pragma unroll
    for (int sh = 32; sh >= 1; sh >>= 1) {
      cgt += __shfl_xor(cgt, sh, 64);
      s   += __shfl_xor(s,   sh, 64);
    }
    __syncthreads();
    if (lane == 0) { redia[wid] = cgt; redfa[wid] = s; }
    __syncthreads();
    if (tid == 0) {
      int c = 0; float tt = 0.0f;
      #pragma unroll
      for (int w = 0; w < 16; ++w) { c += redia[w]; tt += redfa[w]; }
      tot = tt + (float)(k - c) * vk;
    }
  }
  if (tid == 0) {
    atomicAdd(&facc[2], tot);
    __threadfence();
    int t = atomicAdd(ticket, 1);
    if (t == NB - 1) {                       // last block finalizes
      float f1 = atomicAdd(&facc[1], 0.0f);
      float f2 = atomicAdd(&facc[2], 0.0f);
      float N = (float)iacc[0];
      out[0] = facc[0] / N;                  // LOC_WEIGHT = 1.0
      out[1] = (f1 + f2) / N;
    }
  }
}

extern "C" void kernel_launch(void* const* d_in, const int* in_sizes, int n_in,
                              void* d_out, int out_size, void* d_ws, size_t ws_size,
                              hipStream_t stream) {
  const float* loc     = (const float*)d_in[0];
  const float* conf    = (const float*)d_in[1];
  const float* targets = (const float*)d_in[2];
  const float* priors  = (const float*)d_in[3];
  float* out = (float*)d_out;

  // workspace layout (bytes):
  //   0      facc[4]          16     iacc        20     ticket
  //   32     num_pos[32]      256    lsum_part[1024]    4352  pcnt_part[1024]
  //   8448   bestPrChunk[NB*NOBJ*CHUNKS] u64 (131072)
  //   139520 conf_t[NROWS]    1257216 lse[NROWS]
  char* ws = (char*)d_ws;
  float* facc    = (float*)ws;
  int*   iacc    = (int*)(ws + 16);
  int*   ticket  = (int*)(ws + 20);
  int*   num_pos = (int*)(ws + 32);
  float* lsum_part = (float*)(ws + 256);
  int*   pcnt_part = (int*)(ws + 4352);
  unsigned long long* bestPrChunk = (unsigned long long*)(ws + 8448);
  int*   conf_t  = (int*)(ws + 139520);
  float* lse     = (float*)(ws + 1257216);

  hipLaunchKernelGGL(k1, dim3(MATCH_BLOCKS + LSE_BLOCKS), dim3(256), 0, stream,
                     loc, conf, targets, priors, bestPrChunk, conf_t,
                     lsum_part, pcnt_part, lse);
  hipLaunchKernelGGL(k2, dim3(1), dim3(256), 0, stream,
                     loc, targets, priors, bestPrChunk, lsum_part, pcnt_part,
                     conf_t, num_pos, facc, iacc, ticket);
  hipLaunchKernelGGL(k3, dim3(NB), dim3(1024), 0, stream,
                     conf, conf_t, lse, num_pos, facc, iacc, ticket, out);
}